// Round 1
// baseline (327.915 us; speedup 1.0000x reference)
//
#include <hip/hip_runtime.h>
#include <hip/hip_bf16.h>

typedef __bf16 bf16x8 __attribute__((ext_vector_type(8)));
typedef __bf16 bf16x4 __attribute__((ext_vector_type(4)));
typedef float  f32x4  __attribute__((ext_vector_type(4)));

#define NB 4
#define TT 4096
#define CC 1024
#define HH 128
#define PS 72
#define MNEG -30000.0f

__device__ inline void gload16(const void* g, void* l) {
  __builtin_amdgcn_global_load_lds(
      (const __attribute__((address_space(1))) void*)g,
      (__attribute__((address_space(3))) void*)l, 16, 0, 0);
}

// ---------------- dtype probe: bf16 vs fp32 storage ----------------
__global__ void detect_dtype(const unsigned int* __restrict__ xw, int* __restrict__ flag) {
  int t = threadIdx.x;
  int cnt = 0;
#pragma unroll
  for (int i = 0; i < 4; ++i) {
    unsigned int w = xw[t + 64 * i];
    int e = (int)((w >> 7) & 0xFFu);
    cnt += (e >= 100 && e <= 135) ? 1 : 0;
  }
  cnt += __shfl_xor(cnt, 1);  cnt += __shfl_xor(cnt, 2);  cnt += __shfl_xor(cnt, 4);
  cnt += __shfl_xor(cnt, 8);  cnt += __shfl_xor(cnt, 16); cnt += __shfl_xor(cnt, 32);
  if (t == 0) *flag = (cnt >= 128) ? 1 : 0;
}

// -------- transpose W [C][H] -> proj-staging tile format, x3 --------
// layout: [kstep=c/64][which][g=(c/8)%8][h][j=c%8]
__global__ __launch_bounds__(256) void transpose_w3(
    const void* __restrict__ Wq, const void* __restrict__ Wk,
    const void* __restrict__ Wv, __bf16* __restrict__ Wt,
    const int* __restrict__ flagp) {
  int isbf = *flagp;
  int which = blockIdx.y;
  const void* W = (which == 0) ? Wq : (which == 1) ? Wk : Wv;
  int idx = blockIdx.x * 256 + threadIdx.x;
  int h = idx >> 10, c = idx & 1023;
  __bf16 val;
  if (isbf) val = ((const __bf16*)W)[c * HH + h];
  else      val = (__bf16)(((const float*)W)[c * HH + h]);
  size_t o = (size_t)(c >> 6) * 24576 + (size_t)which * 8192 +
             (size_t)((c >> 3) & 7) * 1024 + (size_t)h * 8 + (c & 7);
  Wt[o] = val;
}

// ------- fused QKV projection: 12 waves, double-buffered staging -------
// 256 blocks x 768 thr (3 which x 4 rowgroups). M=64, BK=64, 16 K-steps.
// XT xor-swizzled granules; WTs streamed via global_load_lds.
__global__ __launch_bounds__(768) void qkv_proj(
    const void* __restrict__ x, const __bf16* __restrict__ Wt,
    __bf16* __restrict__ q, __bf16* __restrict__ ktl, __bf16* __restrict__ vtl,
    const int* __restrict__ flagp) {
  __shared__ __align__(16) __bf16 XT[2][4096];     // 16 KB
  __shared__ __align__(16) __bf16 WTs[2][24576];   // 96 KB
  int isbf = *flagp;
  int tid = threadIdx.x, lane = tid & 63, wave = tid >> 6;
  int which = wave >> 2, rowgrp = wave & 3;
  int l16 = lane & 15, quad = lane >> 4;
  int row0 = blockIdx.x * 64;
  f32x4 acc[8] = {};

  // ---- staging helper (inlined twice): stage step ss into buffer b ----
#define STAGE(ss, b)                                                          \
  for (int i = wave; i < 56; i += 12) {                                       \
    if (i < 8) {                                                              \
      int row = i * 8 + (lane >> 3), g = lane & 7;                            \
      bf16x8 pk;                                                              \
      if (isbf) {                                                             \
        pk = *(const bf16x8*)((const __bf16*)x + (size_t)(row0 + row) * CC +  \
                              (ss) * 64 + g * 8);                             \
      } else {                                                                \
        const float* xf = (const float*)x + (size_t)(row0 + row) * CC +       \
                          (ss) * 64 + g * 8;                                  \
        f32x4 lo = *(const f32x4*)xf;                                         \
        f32x4 hi = *(const f32x4*)(xf + 4);                                   \
        for (int j = 0; j < 4; ++j) { pk[j] = (__bf16)lo[j]; pk[j+4] = (__bf16)hi[j]; } \
      }                                                                       \
      *(bf16x8*)(&XT[b][g * 512 + (row ^ g) * 8]) = pk;                       \
    } else {                                                                  \
      int j = i - 8;                                                          \
      gload16(Wt + (size_t)(ss) * 24576 + j * 512 + lane * 8,                 \
              &WTs[b][j * 512]);                                              \
    }                                                                         \
  }

  STAGE(0, 0);                           // preload step 0
  for (int s = 0; s < 16; ++s) {
    int cb = s & 1;
    __syncthreads();                     // drains stage(s) [vmcnt0+lgkm before barrier]
    if (s + 1 < 16) { STAGE(s + 1, cb ^ 1); }
#pragma unroll
    for (int t = 0; t < 2; ++t) {
      int g = t * 4 + quad;
      bf16x8 a = *(const bf16x8*)(&XT[cb][g * 512 + ((rowgrp * 16 + l16) ^ g) * 8]);
#pragma unroll
      for (int nt = 0; nt < 8; ++nt) {
        bf16x8 b = *(const bf16x8*)(&WTs[cb][(size_t)which * 8192 + g * 1024 + (nt * 16 + l16) * 8]);
        acc[nt] = __builtin_amdgcn_mfma_f32_16x16x32_bf16(a, b, acc[nt], 0, 0, 0);
      }
    }
  }
#undef STAGE

  int tile = row0 >> 6;
  if (which == 0) {
#pragma unroll
    for (int nt = 0; nt < 8; ++nt)
#pragma unroll
      for (int r = 0; r < 4; ++r) {
        int row = row0 + rowgrp * 16 + quad * 4 + r;
        q[(size_t)row * HH + nt * 16 + l16] = (__bf16)acc[nt][r];
      }
  } else if (which == 1) {
    __bf16* kb = ktl + (size_t)tile * 8192;
#pragma unroll
    for (int nt = 0; nt < 8; ++nt) {
      int h = nt * 16 + l16, g = h >> 3, j = h & 7;
#pragma unroll
      for (int r = 0; r < 4; ++r) {
        int sidx = rowgrp * 16 + quad * 4 + r;
        kb[g * 512 + sidx * 8 + j] = (__bf16)acc[nt][r];
      }
    }
  } else {
    __bf16* vb = vtl + (size_t)tile * 8192;
#pragma unroll
    for (int nt = 0; nt < 8; ++nt) {
      int h = nt * 16 + l16;
      int sb = rowgrp * 16 + quad * 4;
      bf16x4 pk;
#pragma unroll
      for (int r = 0; r < 4; ++r) pk[r] = (__bf16)acc[nt][r];
      *(bf16x4*)(vb + (sb >> 3) * 1024 + h * 8 + (sb & 7)) = pk;
    }
  }
}

// ------- flash attention: in-block split-K, 16 waves = 4 kgroups x 4 rowwaves -------
// Fixed-max softmax (p = exp2(s*SC - M0)) makes partial (O,l) combine a plain sum:
// kgroups 1..3 dump partials to LDS, one barrier, kgroup 0 sums + normalizes + stores.
// K tiled [tile][g=h/8][s][8]; V tiled [tile][gs=s/8][h][8]. No barriers in main loop.
__global__ __launch_bounds__(1024) void flash_attn(
    const __bf16* __restrict__ q, const __bf16* __restrict__ ktl,
    const __bf16* __restrict__ vtl, void* __restrict__ out,
    const int* __restrict__ flagp) {
  __shared__ __align__(16) __bf16 PL[16][16 * PS];   // per-wave P staging, 36.9 KB
  __shared__ float CMB[3][64][132];                  // partial O from kg 1..3, 101.4 KB (pad->2-way free)
  __shared__ float CL[3][64];                        // partial l from kg 1..3

  int bx = blockIdx.x;
  int qt = bx & 63;                      // 256 blocks == 256 CUs: no ordering tricks needed
  int batch = bx >> 6;

  int tid = threadIdx.x, lane = tid & 63, wave = tid >> 6;
  int kg = wave >> 2, rowgrp = wave & 3; // kgroup splits K-range, rowgrp splits q-rows
  int l16 = lane & 15, quad = lane >> 4;
  int qb = qt * 64;
  const __bf16* qp  = q   + (size_t)batch * TT * HH;
  const __bf16* ktb = ktl + (size_t)batch * TT * HH;
  const __bf16* vtb = vtl + (size_t)batch * TT * HH;

  bf16x8 qf[4];
  {
    const __bf16* qrow = qp + (size_t)(qb + rowgrp * 16 + l16) * HH + quad * 8;
#pragma unroll
    for (int ks = 0; ks < 4; ++ks) qf[ks] = *(const bf16x8*)(qrow + ks * 32);
  }
  bf16x8 onesf;
#pragma unroll
  for (int j = 0; j < 8; ++j) onesf[j] = (l16 == 0) ? (__bf16)1.0f : (__bf16)0.0f;

  f32x4 acc_o[8] = {};
  f32x4 acc_l = {};
  const float SC = 0.0450842200278f;     // log2(e)/32
  const float M0 = 4.0f;
  int qrl = qb + rowgrp * 16 + quad * 4;

  for (int jt = kg; jt <= qt; jt += 4) {
    const __bf16* kt  = ktb + (size_t)jt * 8192;
    const __bf16* vt2 = vtb + (size_t)jt * 8192;

    // all 16 K fragments issued up front (independent)
    bf16x8 kf[4][4];
#pragma unroll
    for (int ks = 0; ks < 4; ++ks)
#pragma unroll
      for (int kn = 0; kn < 4; ++kn)
        kf[ks][kn] = *(const bf16x8*)(kt + ((4 * ks + quad) * 64 + kn * 16 + l16) * 8);

    f32x4 accs[4] = {};
#pragma unroll
    for (int ks = 0; ks < 4; ++ks)
#pragma unroll
      for (int kn = 0; kn < 4; ++kn)
        accs[kn] = __builtin_amdgcn_mfma_f32_16x16x32_bf16(qf[ks], kf[ks][kn], accs[kn], 0, 0, 0);

    // V fragments issued now; exp2 + P-LDS phase below hides their latency
    bf16x8 vf[2][8];
#pragma unroll
    for (int ks2 = 0; ks2 < 2; ++ks2)
#pragma unroll
      for (int nt = 0; nt < 8; ++nt)
        vf[ks2][nt] = *(const bf16x8*)(vt2 + (ks2 * 4 + quad) * 1024 + (nt * 16 + l16) * 8);

    // fixed-max softmax: p = exp2(s*SC - M0); mask only on diagonal tile
    float pv[4][4];
    if (jt == qt) {
#pragma unroll
      for (int nt = 0; nt < 4; ++nt) {
        int kcol = jt * 64 + nt * 16 + l16;
#pragma unroll
        for (int r = 0; r < 4; ++r) {
          float z = fmaf(accs[nt][r], SC, -M0);
          z = (kcol <= qrl + r) ? z : MNEG;
          pv[nt][r] = exp2f(z);
        }
      }
    } else {
#pragma unroll
      for (int nt = 0; nt < 4; ++nt)
#pragma unroll
        for (int r = 0; r < 4; ++r)
          pv[nt][r] = exp2f(fmaf(accs[nt][r], SC, -M0));
    }

    // P -> per-wave LDS (C/D -> A-operand)
    __bf16* pw = &PL[wave][0];
#pragma unroll
    for (int nt = 0; nt < 4; ++nt)
#pragma unroll
      for (int r = 0; r < 4; ++r)
        pw[(quad * 4 + r) * PS + nt * 16 + l16] = (__bf16)pv[nt][r];

    // O += P V ; l += P * ones
#pragma unroll
    for (int ks2 = 0; ks2 < 2; ++ks2) {
      bf16x8 pa = *(const bf16x8*)(pw + l16 * PS + ks2 * 32 + quad * 8);
      acc_l = __builtin_amdgcn_mfma_f32_16x16x32_bf16(pa, onesf, acc_l, 0, 0, 0);
#pragma unroll
      for (int nt = 0; nt < 8; ++nt)
        acc_o[nt] = __builtin_amdgcn_mfma_f32_16x16x32_bf16(pa, vf[ks2][nt], acc_o[nt], 0, 0, 0);
    }
  }

  // ---- combine partials across kgroups (plain sums; fixed-max => no rescale) ----
  int qrow = rowgrp * 16 + quad * 4;
  if (kg > 0) {
#pragma unroll
    for (int nt = 0; nt < 8; ++nt)
#pragma unroll
      for (int r = 0; r < 4; ++r)
        CMB[kg - 1][qrow + r][nt * 16 + l16] = acc_o[nt][r];
    if (l16 == 0) {
#pragma unroll
      for (int r = 0; r < 4; ++r) CL[kg - 1][qrow + r] = acc_l[r];
    }
  }
  __syncthreads();
  if (kg == 0) {
    int isbf = *flagp;
    float inv[4];
#pragma unroll
    for (int r = 0; r < 4; ++r) {
      float lr = __shfl(acc_l[r], lane & 48);
      lr += CL[0][qrow + r] + CL[1][qrow + r] + CL[2][qrow + r];
      inv[r] = 1.f / fmaxf(lr, 1e-30f);
    }
    __bf16* ob = (__bf16*)out + (size_t)batch * TT * HH;
    float*  of = (float*)out  + (size_t)batch * TT * HH;
#pragma unroll
    for (int nt = 0; nt < 8; ++nt)
#pragma unroll
      for (int r = 0; r < 4; ++r) {
        int row = qb + qrow + r;
        int col = nt * 16 + l16;
        float val = acc_o[nt][r] + CMB[0][qrow + r][col] + CMB[1][qrow + r][col] +
                    CMB[2][qrow + r][col];
        val *= inv[r];
        size_t idx = (size_t)row * HH + col;
        if (isbf) ob[idx] = (__bf16)val;
        else      of[idx] = val;
      }
  }
}

extern "C" void kernel_launch(void* const* d_in, const int* in_sizes, int n_in,
                              void* d_out, int out_size, void* d_ws, size_t ws_size,
                              hipStream_t stream) {
  const void* x  = d_in[0];
  const void* Wq = d_in[1];
  const void* Wk = d_in[2];
  const void* Wv = d_in[3];
  char* wsb = (char*)d_ws;
  __bf16* q   = (__bf16*)wsb;
  __bf16* ktl = q   + (size_t)NB * TT * HH;
  __bf16* vtl = ktl + (size_t)NB * TT * HH;
  __bf16* wt  = vtl + (size_t)NB * TT * HH;
  size_t base = (((size_t)(3 * NB * TT * HH + 3 * CC * HH) * 2) + 255) & ~(size_t)255;
  int* flag = (int*)(wsb + base);
  (void)ws_size; (void)in_sizes; (void)n_in; (void)out_size;

  detect_dtype<<<1, 64, 0, stream>>>((const unsigned int*)x, flag);
  transpose_w3<<<dim3(512, 3), 256, 0, stream>>>(Wq, Wk, Wv, wt, flag);
  qkv_proj<<<256, 768, 0, stream>>>(x, wt, q, ktl, vtl, flag);
  flash_attn<<<NB * 64, 1024, 0, stream>>>(q, ktl, vtl, d_out, flag);
}

// Round 2
// 190.578 us; speedup vs baseline: 1.7206x; 1.7206x over previous
//
#include <hip/hip_runtime.h>
#include <hip/hip_bf16.h>

typedef __bf16 bf16x8 __attribute__((ext_vector_type(8)));
typedef __bf16 bf16x4 __attribute__((ext_vector_type(4)));
typedef float  f32x4  __attribute__((ext_vector_type(4)));

#define NB 4
#define TT 4096
#define CC 1024
#define HH 128
#define PS 72
#define MNEG -30000.0f

__device__ inline void gload16(const void* g, void* l) {
  __builtin_amdgcn_global_load_lds(
      (const __attribute__((address_space(1))) void*)g,
      (__attribute__((address_space(3))) void*)l, 16, 0, 0);
}

// ---------------- dtype probe: bf16 vs fp32 storage ----------------
__global__ void detect_dtype(const unsigned int* __restrict__ xw, int* __restrict__ flag) {
  int t = threadIdx.x;
  int cnt = 0;
#pragma unroll
  for (int i = 0; i < 4; ++i) {
    unsigned int w = xw[t + 64 * i];
    int e = (int)((w >> 7) & 0xFFu);
    cnt += (e >= 100 && e <= 135) ? 1 : 0;
  }
  cnt += __shfl_xor(cnt, 1);  cnt += __shfl_xor(cnt, 2);  cnt += __shfl_xor(cnt, 4);
  cnt += __shfl_xor(cnt, 8);  cnt += __shfl_xor(cnt, 16); cnt += __shfl_xor(cnt, 32);
  if (t == 0) *flag = (cnt >= 128) ? 1 : 0;
}

// -------- transpose W [C][H] -> proj-staging tile format, x3 --------
// layout: [kstep=c/64][which][g=(c/8)%8][h][j=c%8]
__global__ __launch_bounds__(256) void transpose_w3(
    const void* __restrict__ Wq, const void* __restrict__ Wk,
    const void* __restrict__ Wv, __bf16* __restrict__ Wt,
    const int* __restrict__ flagp) {
  int isbf = *flagp;
  int which = blockIdx.y;
  const void* W = (which == 0) ? Wq : (which == 1) ? Wk : Wv;
  int idx = blockIdx.x * 256 + threadIdx.x;
  int h = idx >> 10, c = idx & 1023;
  __bf16 val;
  if (isbf) val = ((const __bf16*)W)[c * HH + h];
  else      val = (__bf16)(((const float*)W)[c * HH + h]);
  size_t o = (size_t)(c >> 6) * 24576 + (size_t)which * 8192 +
             (size_t)((c >> 3) & 7) * 1024 + (size_t)h * 8 + (c & 7);
  Wt[o] = val;
}

// ------- fused QKV projection: 12 waves, double-buffered staging -------
// 256 blocks x 768 thr (3 which x 4 rowgroups). M=64, BK=64, 16 K-steps.
// XT xor-swizzled granules; WTs streamed via global_load_lds.
__global__ __launch_bounds__(768) void qkv_proj(
    const void* __restrict__ x, const __bf16* __restrict__ Wt,
    __bf16* __restrict__ q, __bf16* __restrict__ ktl, __bf16* __restrict__ vtl,
    const int* __restrict__ flagp) {
  __shared__ __align__(16) __bf16 XT[2][4096];     // 16 KB
  __shared__ __align__(16) __bf16 WTs[2][24576];   // 96 KB
  int isbf = *flagp;
  int tid = threadIdx.x, lane = tid & 63, wave = tid >> 6;
  int which = wave >> 2, rowgrp = wave & 3;
  int l16 = lane & 15, quad = lane >> 4;
  int row0 = blockIdx.x * 64;
  f32x4 acc[8] = {};

  // ---- staging helper (inlined twice): stage step ss into buffer b ----
#define STAGE(ss, b)                                                          \
  for (int i = wave; i < 56; i += 12) {                                       \
    if (i < 8) {                                                              \
      int row = i * 8 + (lane >> 3), g = lane & 7;                            \
      bf16x8 pk;                                                              \
      if (isbf) {                                                             \
        pk = *(const bf16x8*)((const __bf16*)x + (size_t)(row0 + row) * CC +  \
                              (ss) * 64 + g * 8);                             \
      } else {                                                                \
        const float* xf = (const float*)x + (size_t)(row0 + row) * CC +       \
                          (ss) * 64 + g * 8;                                  \
        f32x4 lo = *(const f32x4*)xf;                                         \
        f32x4 hi = *(const f32x4*)(xf + 4);                                   \
        for (int j = 0; j < 4; ++j) { pk[j] = (__bf16)lo[j]; pk[j+4] = (__bf16)hi[j]; } \
      }                                                                       \
      *(bf16x8*)(&XT[b][g * 512 + (row ^ g) * 8]) = pk;                       \
    } else {                                                                  \
      int j = i - 8;                                                          \
      gload16(Wt + (size_t)(ss) * 24576 + j * 512 + lane * 8,                 \
              &WTs[b][j * 512]);                                              \
    }                                                                         \
  }

  STAGE(0, 0);                           // preload step 0
  for (int s = 0; s < 16; ++s) {
    int cb = s & 1;
    __syncthreads();                     // drains stage(s) [vmcnt0+lgkm before barrier]
    if (s + 1 < 16) { STAGE(s + 1, cb ^ 1); }
#pragma unroll
    for (int t = 0; t < 2; ++t) {
      int g = t * 4 + quad;
      bf16x8 a = *(const bf16x8*)(&XT[cb][g * 512 + ((rowgrp * 16 + l16) ^ g) * 8]);
#pragma unroll
      for (int nt = 0; nt < 8; ++nt) {
        bf16x8 b = *(const bf16x8*)(&WTs[cb][(size_t)which * 8192 + g * 1024 + (nt * 16 + l16) * 8]);
        acc[nt] = __builtin_amdgcn_mfma_f32_16x16x32_bf16(a, b, acc[nt], 0, 0, 0);
      }
    }
  }
#undef STAGE

  int tile = row0 >> 6;
  if (which == 0) {
#pragma unroll
    for (int nt = 0; nt < 8; ++nt)
#pragma unroll
      for (int r = 0; r < 4; ++r) {
        int row = row0 + rowgrp * 16 + quad * 4 + r;
        q[(size_t)row * HH + nt * 16 + l16] = (__bf16)acc[nt][r];
      }
  } else if (which == 1) {
    __bf16* kb = ktl + (size_t)tile * 8192;
#pragma unroll
    for (int nt = 0; nt < 8; ++nt) {
      int h = nt * 16 + l16, g = h >> 3, j = h & 7;
#pragma unroll
      for (int r = 0; r < 4; ++r) {
        int sidx = rowgrp * 16 + quad * 4 + r;
        kb[g * 512 + sidx * 8 + j] = (__bf16)acc[nt][r];
      }
    }
  } else {
    __bf16* vb = vtl + (size_t)tile * 8192;
#pragma unroll
    for (int nt = 0; nt < 8; ++nt) {
      int h = nt * 16 + l16;
      int sb = rowgrp * 16 + quad * 4;
      bf16x4 pk;
#pragma unroll
      for (int r = 0; r < 4; ++r) pk[r] = (__bf16)acc[nt][r];
      *(bf16x4*)(vb + (sb >> 3) * 1024 + h * 8 + (sb & 7)) = pk;
    }
  }
}

// ------- flash attention: in-block split-K, 12 waves = 3 kgroups x 4 rowwaves -------
// __launch_bounds__(768,3): 3 waves/SIMD guaranteed -> VGPR cap 168 >= ~150 body,
// NO spill (round-1 lesson: 1024 thr compiled to 64 VGPR -> 272 MB scratch writes).
// Fixed-max softmax (p = exp2(s*SC - M0)) makes partial (O,l) combine a plain sum:
// kgroups 1..2 dump partials to LDS, one barrier, kgroup 0 sums + normalizes + stores.
// K tiled [tile][g=h/8][s][8]; V tiled [tile][gs=s/8][h][8]. No barriers in main loop.
__global__ __launch_bounds__(768, 3) void flash_attn(
    const __bf16* __restrict__ q, const __bf16* __restrict__ ktl,
    const __bf16* __restrict__ vtl, void* __restrict__ out,
    const int* __restrict__ flagp) {
  __shared__ __align__(16) __bf16 PL[12][16 * PS];   // per-wave P staging, 27.6 KB
  __shared__ float CMB[2][64][132];                  // partial O from kg 1..2, 67.6 KB (pad->2-way free)
  __shared__ float CL[2][64];                        // partial l from kg 1..2

  int bx = blockIdx.x;
  int qt = bx & 63;                      // 256 blocks == 256 CUs
  int batch = bx >> 6;

  int tid = threadIdx.x, lane = tid & 63, wave = tid >> 6;
  int kg = wave >> 2, rowgrp = wave & 3; // kgroup splits K-range, rowgrp splits q-rows
  int l16 = lane & 15, quad = lane >> 4;
  int qb = qt * 64;
  const __bf16* qp  = q   + (size_t)batch * TT * HH;
  const __bf16* ktb = ktl + (size_t)batch * TT * HH;
  const __bf16* vtb = vtl + (size_t)batch * TT * HH;

  bf16x8 qf[4];
  {
    const __bf16* qrow = qp + (size_t)(qb + rowgrp * 16 + l16) * HH + quad * 8;
#pragma unroll
    for (int ks = 0; ks < 4; ++ks) qf[ks] = *(const bf16x8*)(qrow + ks * 32);
  }
  bf16x8 onesf;
#pragma unroll
  for (int j = 0; j < 8; ++j) onesf[j] = (l16 == 0) ? (__bf16)1.0f : (__bf16)0.0f;

  f32x4 acc_o[8] = {};
  f32x4 acc_l = {};
  const float SC = 0.0450842200278f;     // log2(e)/32
  const float M0 = 4.0f;
  int qrl = qb + rowgrp * 16 + quad * 4;

  for (int jt = kg; jt <= qt; jt += 3) {
    const __bf16* kt  = ktb + (size_t)jt * 8192;
    const __bf16* vt2 = vtb + (size_t)jt * 8192;

    // all 16 K fragments issued up front (independent)
    bf16x8 kf[4][4];
#pragma unroll
    for (int ks = 0; ks < 4; ++ks)
#pragma unroll
      for (int kn = 0; kn < 4; ++kn)
        kf[ks][kn] = *(const bf16x8*)(kt + ((4 * ks + quad) * 64 + kn * 16 + l16) * 8);

    f32x4 accs[4] = {};
#pragma unroll
    for (int ks = 0; ks < 4; ++ks)
#pragma unroll
      for (int kn = 0; kn < 4; ++kn)
        accs[kn] = __builtin_amdgcn_mfma_f32_16x16x32_bf16(qf[ks], kf[ks][kn], accs[kn], 0, 0, 0);

    // V fragments issued now; exp2 + P-LDS phase below hides their latency
    bf16x8 vf[2][8];
#pragma unroll
    for (int ks2 = 0; ks2 < 2; ++ks2)
#pragma unroll
      for (int nt = 0; nt < 8; ++nt)
        vf[ks2][nt] = *(const bf16x8*)(vt2 + (ks2 * 4 + quad) * 1024 + (nt * 16 + l16) * 8);

    // fixed-max softmax: p = exp2(s*SC - M0); mask only on diagonal tile
    float pv[4][4];
    if (jt == qt) {
#pragma unroll
      for (int nt = 0; nt < 4; ++nt) {
        int kcol = jt * 64 + nt * 16 + l16;
#pragma unroll
        for (int r = 0; r < 4; ++r) {
          float z = fmaf(accs[nt][r], SC, -M0);
          z = (kcol <= qrl + r) ? z : MNEG;
          pv[nt][r] = exp2f(z);
        }
      }
    } else {
#pragma unroll
      for (int nt = 0; nt < 4; ++nt)
#pragma unroll
        for (int r = 0; r < 4; ++r)
          pv[nt][r] = exp2f(fmaf(accs[nt][r], SC, -M0));
    }

    // P -> per-wave LDS (C/D -> A-operand)
    __bf16* pw = &PL[wave][0];
#pragma unroll
    for (int nt = 0; nt < 4; ++nt)
#pragma unroll
      for (int r = 0; r < 4; ++r)
        pw[(quad * 4 + r) * PS + nt * 16 + l16] = (__bf16)pv[nt][r];

    // O += P V ; l += P * ones
#pragma unroll
    for (int ks2 = 0; ks2 < 2; ++ks2) {
      bf16x8 pa = *(const bf16x8*)(pw + l16 * PS + ks2 * 32 + quad * 8);
      acc_l = __builtin_amdgcn_mfma_f32_16x16x32_bf16(pa, onesf, acc_l, 0, 0, 0);
#pragma unroll
      for (int nt = 0; nt < 8; ++nt)
        acc_o[nt] = __builtin_amdgcn_mfma_f32_16x16x32_bf16(pa, vf[ks2][nt], acc_o[nt], 0, 0, 0);
    }
  }

  // ---- combine partials across kgroups (plain sums; fixed-max => no rescale) ----
  int qrow = rowgrp * 16 + quad * 4;
  if (kg > 0) {
#pragma unroll
    for (int nt = 0; nt < 8; ++nt)
#pragma unroll
      for (int r = 0; r < 4; ++r)
        CMB[kg - 1][qrow + r][nt * 16 + l16] = acc_o[nt][r];
    if (l16 == 0) {
#pragma unroll
      for (int r = 0; r < 4; ++r) CL[kg - 1][qrow + r] = acc_l[r];
    }
  }
  __syncthreads();
  if (kg == 0) {
    int isbf = *flagp;
    float inv[4];
#pragma unroll
    for (int r = 0; r < 4; ++r) {
      float lr = __shfl(acc_l[r], lane & 48);
      lr += CL[0][qrow + r] + CL[1][qrow + r];
      inv[r] = 1.f / fmaxf(lr, 1e-30f);
    }
    __bf16* ob = (__bf16*)out + (size_t)batch * TT * HH;
    float*  of = (float*)out  + (size_t)batch * TT * HH;
#pragma unroll
    for (int nt = 0; nt < 8; ++nt)
#pragma unroll
      for (int r = 0; r < 4; ++r) {
        int row = qb + qrow + r;
        int col = nt * 16 + l16;
        float val = acc_o[nt][r] + CMB[0][qrow + r][col] + CMB[1][qrow + r][col];
        val *= inv[r];
        size_t idx = (size_t)row * HH + col;
        if (isbf) ob[idx] = (__bf16)val;
        else      of[idx] = val;
      }
  }
}

extern "C" void kernel_launch(void* const* d_in, const int* in_sizes, int n_in,
                              void* d_out, int out_size, void* d_ws, size_t ws_size,
                              hipStream_t stream) {
  const void* x  = d_in[0];
  const void* Wq = d_in[1];
  const void* Wk = d_in[2];
  const void* Wv = d_in[3];
  char* wsb = (char*)d_ws;
  __bf16* q   = (__bf16*)wsb;
  __bf16* ktl = q   + (size_t)NB * TT * HH;
  __bf16* vtl = ktl + (size_t)NB * TT * HH;
  __bf16* wt  = vtl + (size_t)NB * TT * HH;
  size_t base = (((size_t)(3 * NB * TT * HH + 3 * CC * HH) * 2) + 255) & ~(size_t)255;
  int* flag = (int*)(wsb + base);
  (void)ws_size; (void)in_sizes; (void)n_in; (void)out_size;

  detect_dtype<<<1, 64, 0, stream>>>((const unsigned int*)x, flag);
  transpose_w3<<<dim3(512, 3), 256, 0, stream>>>(Wq, Wk, Wv, wt, flag);
  qkv_proj<<<256, 768, 0, stream>>>(x, wt, q, ktl, vtl, flag);
  flash_attn<<<NB * 64, 768, 0, stream>>>(q, ktl, vtl, d_out, flag);
}